// Round 1
// baseline (20152.440 us; speedup 1.0000x reference)
//
#include <hip/hip_runtime.h>

// Problem constants (from reference setup_inputs)
#define BATCH 32
#define FIN   256
#define FOUT  256
#define HW    56
#define NPIX  (HW * HW)      // 3136
#define XS_W  60             // padded LDS row stride (58 used) -> 16B-aligned rows
#define XS_H  58
#define NGROUPS (NPIX / 4)   // 784 groups of 4 horizontal pixels (56 % 4 == 0)

// One block per (b, fo). Loop fi: stage x[b,fi] (58x58 zero halo) to LDS,
// fold wm = weight*mask into 9 uniform scalars, accumulate 4-pixel register
// blocks. blockIdx = b*256+fo keeps same-sample blocks adjacent for L2 reuse.
__global__ __launch_bounds__(256) void conv_dwa_fp32(
    const float* __restrict__ x,
    const float* __restrict__ m,
    const float* __restrict__ weight,
    const float* __restrict__ bias,
    float* __restrict__ out)
{
    __shared__ float xs[XS_H * XS_W];

    const int tid = threadIdx.x;
    const int blk = blockIdx.x;
    const int b   = blk >> 8;     // / FOUT
    const int fo  = blk & 255;    // % FOUT

    const float* xb = x + (size_t)b * FIN * NPIX;
    const float* mb = m + ((size_t)b * FOUT + fo) * (FIN * 9);
    const float* wb = weight + (size_t)fo * (FIN * 9);

    float acc[4][4];
#pragma unroll
    for (int g = 0; g < 4; ++g)
#pragma unroll
        for (int i = 0; i < 4; ++i) acc[g][i] = 0.0f;

    // Per-thread group geometry: group gi covers pixels [gi*4, gi*4+4) in one row.
    int rowbase[4];  // LDS offset of the group's top-left halo element
#pragma unroll
    for (int g = 0; g < 4; ++g) {
        int gi = tid + g * 256;
        int p0 = gi * 4;
        int gh = p0 / HW;
        int gw = p0 - gh * HW;
        rowbase[g] = gh * XS_W + gw;   // halo coords: pixel (h,w), tap(kh,kw) -> xs[(h+kh)*XS_W + w+kw]
    }

    for (int fi = 0; fi < FIN; ++fi) {
        const float* xp = xb + (size_t)fi * NPIX;

        __syncthreads();  // previous iteration's readers done before overwrite
        // Stage 58x58 halo tile (row stride XS_W=60)
        for (int idx = tid; idx < XS_H * 58; idx += 256) {
            int hh = idx / 58;            // 0..57
            int ww = idx - hh * 58;       // 0..57
            int h = hh - 1, w = ww - 1;
            float v = 0.0f;
            if ((unsigned)h < HW && (unsigned)w < HW) v = xp[h * HW + w];
            xs[hh * XS_W + ww] = v;
        }

        // Masked weights: uniform across the block (b, fo, fi uniform) -> scalar loads
        float wm[9];
#pragma unroll
        for (int j = 0; j < 9; ++j) wm[j] = wb[fi * 9 + j] * mb[fi * 9 + j];

        __syncthreads();

#pragma unroll
        for (int g = 0; g < 4; ++g) {
            if (tid + g * 256 >= NGROUPS) break;   // only threads <16 have a 4th group
            const float* row0 = &xs[rowbase[g]];
#pragma unroll
            for (int kh = 0; kh < 3; ++kh) {
                const float* r = row0 + kh * XS_W;
                float s0 = r[0], s1 = r[1], s2 = r[2], s3 = r[3], s4 = r[4], s5 = r[5];
                const float w0 = wm[3 * kh + 0], w1 = wm[3 * kh + 1], w2 = wm[3 * kh + 2];
                acc[g][0] = fmaf(s2, w2, fmaf(s1, w1, fmaf(s0, w0, acc[g][0])));
                acc[g][1] = fmaf(s3, w2, fmaf(s2, w1, fmaf(s1, w0, acc[g][1])));
                acc[g][2] = fmaf(s4, w2, fmaf(s3, w1, fmaf(s2, w0, acc[g][2])));
                acc[g][3] = fmaf(s5, w2, fmaf(s4, w1, fmaf(s3, w0, acc[g][3])));
            }
        }
    }

    // Epilogue: add bias, store 4 consecutive floats per group (16B coalesced)
    const float bv = bias[fo];
    float* ob = out + ((size_t)b * FOUT + fo) * NPIX;
#pragma unroll
    for (int g = 0; g < 4; ++g) {
        int gi = tid + g * 256;
        if (gi >= NGROUPS) break;
        float4 v;
        v.x = acc[g][0] + bv;
        v.y = acc[g][1] + bv;
        v.z = acc[g][2] + bv;
        v.w = acc[g][3] + bv;
        *(float4*)(ob + gi * 4) = v;
    }
}

extern "C" void kernel_launch(void* const* d_in, const int* in_sizes, int n_in,
                              void* d_out, int out_size, void* d_ws, size_t ws_size,
                              hipStream_t stream) {
    const float* x      = (const float*)d_in[0];
    const float* m      = (const float*)d_in[1];
    const float* weight = (const float*)d_in[2];
    const float* bias   = (const float*)d_in[3];
    float* out          = (float*)d_out;

    dim3 grid(BATCH * FOUT);  // 8192 blocks, b-major for L2 locality
    dim3 block(256);
    conv_dwa_fp32<<<grid, block, 0, stream>>>(x, m, weight, bias, out);
}

// Round 2
// 485.392 us; speedup vs baseline: 41.5179x; 41.5179x over previous
//
#include <hip/hip_runtime.h>
#include <hip/hip_bf16.h>

typedef __attribute__((ext_vector_type(8))) short short8;
typedef __attribute__((ext_vector_type(4))) float f32x4;

#define BATCH 32
#define NCH   256          // FIN == FOUT == 256
#define HW    56
#define NPIX  (HW * HW)    // 3136
#define KTOT  (NCH * 9)    // 2304, k = tap*256 + fi
#define XT_R  58           // halo row width
#define XT_NP (XT_R * XT_R) // 3364

#define WM_ELEMS ((size_t)BATCH * NCH * KTOT)      // 18,874,368
#define WM_BYTES (WM_ELEMS * 2)                    // 37,748,736
#define XT_ELEMS ((size_t)BATCH * XT_NP * NCH)     // 27,557,888
#define XT_BYTES (XT_ELEMS * 2)                    // 55,115,776
#define WS_NEEDED (WM_BYTES + XT_BYTES)            // ~92.9 MB

#define GLL16(g, l) __builtin_amdgcn_global_load_lds( \
    (const __attribute__((address_space(1))) void*)(g), \
    (__attribute__((address_space(3))) void*)(l), 16, 0, 0)

// ---------------- prep 1: Wm[b][fo][tap*256+fi] = (weight*m) in bf16 ----------------
__global__ __launch_bounds__(256) void wm_prep(const float* __restrict__ w,
                                               const float* __restrict__ m,
                                               __hip_bfloat16* __restrict__ wmo) {
    const int b = blockIdx.x >> 8, fo = blockIdx.x & 255, fi = threadIdx.x;
    const float* wp = w + ((size_t)fo * NCH + fi) * 9;
    const float* mp = m + (((size_t)b * NCH + fo) * NCH + fi) * 9;
    __hip_bfloat16* op = wmo + ((size_t)b * NCH + fo) * KTOT + fi;
#pragma unroll
    for (int t = 0; t < 9; ++t)
        op[t * NCH] = __float2bfloat16(wp[t] * mp[t]);
}

// ---------------- prep 2: Xt[b][h'][w'][fi] (bf16, zero halo pre-memset) ------------
// grid: ((b*56 + h)*4 + fi_chunk), 64 fi x 56 w per block
__global__ __launch_bounds__(256) void xt_prep(const float* __restrict__ x,
                                               __hip_bfloat16* __restrict__ xt) {
    __shared__ float tile[64 * 57];   // stride 57: conflict-free transposed reads
    const int blk = blockIdx.x;
    const int fc = blk & 3;
    const int h  = (blk >> 2) % HW;
    const int b  = blk / (4 * HW);
    const int t  = threadIdx.x;

    const float* xp = x + ((size_t)(b * NCH + fc * 64)) * NPIX + h * HW;
#pragma unroll
    for (int j = 0; j < 14; ++j) {               // 64*56 = 3584 = 14*256
        int idx = j * 256 + t;
        int fi = idx / 56, w = idx - fi * 56;
        tile[fi * 57 + w] = xp[(size_t)fi * NPIX + w];
    }
    __syncthreads();
    __hip_bfloat16* op = xt + ((size_t)b * XT_NP + (size_t)(h + 1) * XT_R + 1) * NCH + fc * 64;
#pragma unroll
    for (int j = 0; j < 7; ++j) {                // 56*32 = 1792 = 7*256 (2 fi per thread)
        int idx = j * 256 + t;
        int w = idx >> 5, fp = (idx & 31) * 2;
        __hip_bfloat162 v;
        v.x = __float2bfloat16(tile[fp * 57 + w]);
        v.y = __float2bfloat16(tile[(fp + 1) * 57 + w]);
        *(__hip_bfloat162*)(op + (size_t)w * NCH + fp) = v;
    }
}

// ---------------- main: per-sample implicit GEMM, 128x128 tile, BK=32 ---------------
// grid: ((b*2 + fo_tile)*25 + p_tile), 256 threads = 4 waves (2x2 of 64x64)
__global__ __launch_bounds__(256) void gemm_dwa(const __hip_bfloat16* __restrict__ wmg,
                                                const __hip_bfloat16* __restrict__ xt,
                                                const float* __restrict__ bias,
                                                float* __restrict__ out) {
    __shared__ __hip_bfloat16 Alds[128 * 32];
    __shared__ __hip_bfloat16 Blds[128 * 32];

    const int blk = blockIdx.x;
    const int pt = blk % 25;
    const int bf = blk / 25;
    const int ft = bf & 1;
    const int b  = bf >> 1;
    const int tid = threadIdx.x;
    const int lane = tid & 63, wv = tid >> 6;
    const int wvm = wv & 1, wvn = wv >> 1;
    const int fo0 = ft * 128, p0 = pt * 128;

    // staging geometry: chunk c = i*256 + tid; row/n = c>>2; kc = c&3 (8 bf16 per 16B)
    const int kc = tid & 3;
    const int nr = tid >> 2;                 // 0..63 (i=0), +64 for i=1

    // B-side pixel geometry for n = nr and nr+64
    int hwb[2]; int valid[2];
#pragma unroll
    for (int i = 0; i < 2; ++i) {
        int p = p0 + nr + i * 64;
        valid[i] = (p < NPIX);
        int ph = p / HW, pw = p - ph * HW;
        hwb[i] = ph * XT_R + pw;             // + kh*58 + kw gives halo index (zero-pad safe)
    }

    const __hip_bfloat16* wbase = wmg + ((size_t)(b * NCH + fo0)) * KTOT + (size_t)nr * KTOT + kc * 8;
    const __hip_bfloat16* xbase = xt + (size_t)b * XT_NP * NCH;

    f32x4 acc[4][4];
#pragma unroll
    for (int mi = 0; mi < 4; ++mi)
#pragma unroll
        for (int ni = 0; ni < 4; ++ni) acc[mi][ni] = (f32x4)0.0f;

    // fragment read offsets (elements)
    const int arow = wvm * 64 + (lane & 15);
    const int brow = wvn * 64 + (lane & 15);
    const int koff = (lane >> 4) * 8;

    for (int tap = 0; tap < 9; ++tap) {
        const int kh = tap / 3, kw = tap - kh * 3;
        const int tapoff = kh * XT_R + kw;
        const size_t off0 = (size_t)(valid[0] ? hwb[0] + tapoff : XT_NP - 1) * NCH;
        const size_t off1 = (size_t)(valid[1] ? hwb[1] + tapoff : XT_NP - 1) * NCH;
        const __hip_bfloat16* bg0 = xbase + off0 + kc * 8;
        const __hip_bfloat16* bg1 = xbase + off1 + kc * 8;

        for (int s = 0; s < 8; ++s) {
            const int k0 = tap * 256 + s * 32;
            const int fi0 = s * 32;

            __syncthreads();   // prior iteration's frag reads done
            // A tile: 128 rows x 32 k (64B/row), rows nr and nr+64
            GLL16(wbase + k0,              Alds + (size_t)(wv * 64) * 8);
            GLL16(wbase + 64 * KTOT + k0,  Alds + (size_t)(256 + wv * 64) * 8);
            // B tile: Blds[n][k] n-major, k-contiguous
            GLL16(bg0 + fi0,               Blds + (size_t)(wv * 64) * 8);
            GLL16(bg1 + fi0,               Blds + (size_t)(256 + wv * 64) * 8);
            __syncthreads();   // staging (vmcnt) drained

            short8 af[4], bfr[4];
#pragma unroll
            for (int mi = 0; mi < 4; ++mi)
                af[mi] = *(const short8*)(Alds + (size_t)(arow + mi * 16) * 32 + koff);
#pragma unroll
            for (int ni = 0; ni < 4; ++ni)
                bfr[ni] = *(const short8*)(Blds + (size_t)(brow + ni * 16) * 32 + koff);
#pragma unroll
            for (int mi = 0; mi < 4; ++mi)
#pragma unroll
                for (int ni = 0; ni < 4; ++ni)
                    acc[mi][ni] = __builtin_amdgcn_mfma_f32_16x16x32_bf16(
                        af[mi], bfr[ni], acc[mi][ni], 0, 0, 0);
        }
    }

    // epilogue: C[m][n]: m = (lane>>4)*4 + r, n = lane&15 (m89-verified layout)
#pragma unroll
    for (int mi = 0; mi < 4; ++mi) {
#pragma unroll
        for (int r = 0; r < 4; ++r) {
            const int row = fo0 + wvm * 64 + mi * 16 + (lane >> 4) * 4 + r;
            const float bv = bias[row];
            float* op = out + ((size_t)(b * NCH + row)) * NPIX;
#pragma unroll
            for (int ni = 0; ni < 4; ++ni) {
                const int col = p0 + wvn * 64 + ni * 16 + (lane & 15);
                if (col < NPIX) op[col] = acc[mi][ni][r] + bv;
            }
        }
    }
}

// ---------------- round-1 fp32 fallback (if ws too small) ---------------------------
#define XS_W 60
#define XS_H 58
#define NGROUPS (NPIX / 4)
__global__ __launch_bounds__(256) void conv_dwa_fp32(
    const float* __restrict__ x, const float* __restrict__ m,
    const float* __restrict__ weight, const float* __restrict__ bias,
    float* __restrict__ out) {
    __shared__ float xs[XS_H * XS_W];
    const int tid = threadIdx.x, blk = blockIdx.x;
    const int b = blk >> 8, fo = blk & 255;
    const float* xb = x + (size_t)b * NCH * NPIX;
    const float* mb = m + ((size_t)b * NCH + fo) * (NCH * 9);
    const float* wb = weight + (size_t)fo * (NCH * 9);
    float acc[4][4];
#pragma unroll
    for (int g = 0; g < 4; ++g)
#pragma unroll
        for (int i = 0; i < 4; ++i) acc[g][i] = 0.0f;
    int rowbase[4];
#pragma unroll
    for (int g = 0; g < 4; ++g) {
        int p0 = (tid + g * 256) * 4;
        int gh = p0 / HW;
        rowbase[g] = gh * XS_W + (p0 - gh * HW);
    }
    for (int fi = 0; fi < NCH; ++fi) {
        const float* xp = xb + (size_t)fi * NPIX;
        __syncthreads();
        for (int idx = tid; idx < XS_H * 58; idx += 256) {
            int hh = idx / 58, ww = idx - hh * 58;
            int h = hh - 1, w = ww - 1;
            float v = 0.0f;
            if ((unsigned)h < HW && (unsigned)w < HW) v = xp[h * HW + w];
            xs[hh * XS_W + ww] = v;
        }
        float wm9[9];
#pragma unroll
        for (int j = 0; j < 9; ++j) wm9[j] = wb[fi * 9 + j] * mb[fi * 9 + j];
        __syncthreads();
#pragma unroll
        for (int g = 0; g < 4; ++g) {
            if (tid + g * 256 >= NGROUPS) break;
            const float* row0 = &xs[rowbase[g]];
#pragma unroll
            for (int kh = 0; kh < 3; ++kh) {
                const float* r = row0 + kh * XS_W;
                float s0 = r[0], s1 = r[1], s2 = r[2], s3 = r[3], s4 = r[4], s5 = r[5];
                const float w0 = wm9[3 * kh], w1 = wm9[3 * kh + 1], w2 = wm9[3 * kh + 2];
                acc[g][0] = fmaf(s2, w2, fmaf(s1, w1, fmaf(s0, w0, acc[g][0])));
                acc[g][1] = fmaf(s3, w2, fmaf(s2, w1, fmaf(s1, w0, acc[g][1])));
                acc[g][2] = fmaf(s4, w2, fmaf(s3, w1, fmaf(s2, w0, acc[g][2])));
                acc[g][3] = fmaf(s5, w2, fmaf(s4, w1, fmaf(s3, w0, acc[g][3])));
            }
        }
    }
    const float bv = bias[fo];
    float* ob = out + ((size_t)b * NCH + fo) * NPIX;
#pragma unroll
    for (int g = 0; g < 4; ++g) {
        int gi = tid + g * 256;
        if (gi >= NGROUPS) break;
        float4 v;
        v.x = acc[g][0] + bv; v.y = acc[g][1] + bv;
        v.z = acc[g][2] + bv; v.w = acc[g][3] + bv;
        *(float4*)(ob + gi * 4) = v;
    }
}

extern "C" void kernel_launch(void* const* d_in, const int* in_sizes, int n_in,
                              void* d_out, int out_size, void* d_ws, size_t ws_size,
                              hipStream_t stream) {
    const float* x      = (const float*)d_in[0];
    const float* m      = (const float*)d_in[1];
    const float* weight = (const float*)d_in[2];
    const float* bias   = (const float*)d_in[3];
    float* out          = (float*)d_out;

    if (ws_size < WS_NEEDED) {  // constant across calls -> graph-safe
        conv_dwa_fp32<<<dim3(BATCH * NCH), dim3(256), 0, stream>>>(x, m, weight, bias, out);
        return;
    }

    __hip_bfloat16* wmv = (__hip_bfloat16*)d_ws;
    __hip_bfloat16* xtv = (__hip_bfloat16*)((char*)d_ws + WM_BYTES);

    hipMemsetAsync(xtv, 0, XT_BYTES, stream);                       // zero halo
    wm_prep<<<dim3(BATCH * NCH), dim3(256), 0, stream>>>(weight, m, wmv);
    xt_prep<<<dim3(BATCH * HW * 4), dim3(256), 0, stream>>>(x, xtv);
    gemm_dwa<<<dim3(BATCH * 2 * 25), dim3(256), 0, stream>>>(wmv, xtv, bias, out);
}

// Round 3
// 347.102 us; speedup vs baseline: 58.0591x; 1.3984x over previous
//
#include <hip/hip_runtime.h>
#include <hip/hip_bf16.h>

typedef __attribute__((ext_vector_type(8))) short short8;
typedef __attribute__((ext_vector_type(4))) short short4v;
typedef __attribute__((ext_vector_type(4))) float f32x4;

#define BATCH 32
#define NCH   256
#define HW    56
#define NPIX  3136
#define XT_R  58

// Xt layout: [b][s8][hh58][ww58][fi32] bf16  (fi-chunk-major, halo built in)
#define XT_SLAB   (XT_R * XT_R * 32 * 2)            // 215,296 B per (b,s)
#define XT_BYTES  ((size_t)BATCH * 8 * XT_SLAB)     // 55,115,776
// Wm layout: [b][s8][tap9][fo256][fi32] bf16
#define WM_TAP    (256 * 32 * 2)                    // 16,384 B
#define WM_SLAB   (9 * WM_TAP)                      // 147,456 B per (b,s)
#define WM_B      (8 * WM_SLAB)                     // 1,179,648 B per b
#define WM_BYTES  ((size_t)BATCH * WM_B)            // 37,748,736
#define WS_NEEDED (XT_BYTES + WM_BYTES)             // ~92.9 MB (Xt first: B-stage overrun pads into Wm)

#define GLL16(g, l) __builtin_amdgcn_global_load_lds( \
    (const __attribute__((address_space(1))) void*)(g), \
    (__attribute__((address_space(3))) void*)(l), 16, 0, 0)

static __device__ __forceinline__ short f2bf(float f) {
    union { __hip_bfloat16 h; short s; } u;
    u.h = __float2bfloat16(f);
    return u.s;
}

// ---------------- halo zero: only the 58x58 border of each (b,s) slab --------------
__global__ __launch_bounds__(256) void halo_zero(char* xtb) {
    const int t = threadIdx.x;
    unsigned* p = (unsigned*)(xtb + (size_t)blockIdx.x * XT_SLAB);
    for (int i = t; i < 928; i += 256) { p[i] = 0u; p[57 * 928 + i] = 0u; }  // rows 0, 57
    for (int j = t; j < 896; j += 256) {                                     // cols 0, 57
        int r = (j >> 4) + 1, c = j & 15;
        p[r * 928 + c] = 0u;
        p[r * 928 + 912 + c] = 0u;
    }
}

// ---------------- wm prep: [b][s][tap][fo][fi32] = bf16(weight*m) ------------------
// block = (b, fo); float4 reads, LDS round-trip, 4B coalesced writes
__global__ __launch_bounds__(256) void wm_prep(const float* __restrict__ w,
                                               const float* __restrict__ m,
                                               char* __restrict__ wmb) {
    __shared__ short prod[2304];   // [fi][tap]
    const int b = blockIdx.x >> 8, fo = blockIdx.x & 255, t = threadIdx.x;
    const float4* m4 = (const float4*)(m + ((size_t)(b * NCH + fo)) * 2304);
    const float4* w4 = (const float4*)(w + (size_t)fo * 2304);
#pragma unroll
    for (int i = 0; i < 3; ++i) {
        int idx = i * 256 + t;
        if (idx < 576) {
            float4 a = w4[idx], mm = m4[idx];
            short4v s;
            s.x = f2bf(a.x * mm.x); s.y = f2bf(a.y * mm.y);
            s.z = f2bf(a.z * mm.z); s.w = f2bf(a.w * mm.w);
            ((short4v*)prod)[idx] = s;
        }
    }
    __syncthreads();
    char* ob = wmb + (size_t)b * WM_B + fo * 64;
#pragma unroll
    for (int i = 0; i < 5; ++i) {
        int q = i * 256 + t;
        if (q < 1152) {
            int o = q * 2;
            int s = o / 288, r = o - s * 288;
            int tap = r >> 5, fi = r & 31;
            unsigned lo = (unsigned short)prod[(s * 32 + fi) * 9 + tap];
            unsigned hi = (unsigned short)prod[(s * 32 + fi + 1) * 9 + tap];
            *(unsigned*)(ob + s * WM_SLAB + tap * WM_TAP + fi * 2) = lo | (hi << 16);
        }
    }
}

// ---------------- xt prep: [b][s][hh][ww][fi32] interior (halo pre-zeroed) ---------
// block = (b, h): transpose one image row across all 256 fi
__global__ __launch_bounds__(256) void xt_prep(const float* __restrict__ x,
                                               char* __restrict__ xtb) {
    __shared__ short xl[NCH * HW];   // [fi][w], 57,344 B
    const int blk = blockIdx.x;
    const int b = blk / HW, h = blk % HW, t = threadIdx.x;
    const float4* x4 = (const float4*)(x + (size_t)b * NCH * NPIX);
    const int rowb = h * 14;
#pragma unroll
    for (int i = 0; i < 14; ++i) {             // 3584 float4 = 256 fi x 14
        int c = i * 256 + t;
        int fi = c / 14, j = c - fi * 14;
        float4 v = x4[(size_t)fi * 784 + rowb + j];
        short4v s;
        s.x = f2bf(v.x); s.y = f2bf(v.y); s.z = f2bf(v.z); s.w = f2bf(v.w);
        ((short4v*)xl)[fi * 14 + j] = s;
    }
    __syncthreads();
    char* ob = xtb + (size_t)(b * 8) * XT_SLAB + (h + 1) * 3712 + 64;
#pragma unroll
    for (int i = 0; i < 28; ++i) {             // 7168 fi-pairs = 8s x 56ww x 16
        int q = i * 256 + t;
        int s = q / 896, rr = q - s * 896;
        int ww = rr >> 4, fp = rr & 15;
        int fi = s * 32 + 2 * fp;
        unsigned lo = (unsigned short)xl[fi * HW + ww];
        unsigned hi = (unsigned short)xl[(fi + 1) * HW + ww];
        *(unsigned*)(ob + s * XT_SLAB + ww * 64 + fp * 4) = lo | (hi << 16);
    }
}

// ---------------- main GEMM: block = 64 fo x 448 px (8 rows), K-loop = 8 fi-chunks -
// per fi-step: stage A(64x9x32) + B(10x58x32 halo), then 9 taps x 252 MFMA/wave
__global__ __launch_bounds__(256, 2) void gemm_dwa(const char* __restrict__ xtb,
                                                   const char* __restrict__ wmb,
                                                   const float* __restrict__ bias,
                                                   float* __restrict__ out) {
    __shared__ short Alds[2304 * 8];   // 36,864 B: [tap][fo64][fi32]
    __shared__ short Blds[2560 * 8];   // 40,960 B: [px 10x58][fi32] (+pad for uniform staging)

    const int tid = threadIdx.x, lane = tid & 63, wv = tid >> 6;
    const int ln = lane & 15, kg = lane >> 4;

    // XCD swizzle: pin each sample's working set to one XCD's L2 (perf heuristic only)
    const int blk = blockIdx.x;              // 896 = 8 xcd * 112
    const int xcd = blk & 7, slot = blk >> 3;
    const int b = xcd + 8 * (slot / 28);
    const int inner = slot % 28;
    const int ft = inner / 7, rt = inner % 7;
    const int fo0 = ft * 64, h0 = rt * 8;

    // per-lane B fragment pixel bases (halo-tile linear index, row stride 58)
    int pbase[7];
#pragma unroll
    for (int ni = 0; ni < 7; ++ni) {
        int p = wv * 112 + ni * 16 + ln;
        int hh = p / 56;
        pbase[ni] = hh * XT_R + (p - hh * 56);
    }

    const char* Ag = wmb + (size_t)b * WM_B + fo0 * 64;
    const char* Bg = xtb + (size_t)(b * 8) * XT_SLAB + h0 * 3712;

    f32x4 acc[4][7];
#pragma unroll
    for (int mi = 0; mi < 4; ++mi)
#pragma unroll
        for (int ni = 0; ni < 7; ++ni) acc[mi][ni] = (f32x4)0.0f;

    for (int s = 0; s < 8; ++s) {
        const char* ag = Ag + s * WM_SLAB;
        const char* bg = Bg + (size_t)s * XT_SLAB;

        __syncthreads();   // prior frag reads done
#pragma unroll
        for (int i = 0; i < 9; ++i) {          // A: 2304 chunks of 16B
            int c = i * 256 + tid;
            GLL16(ag + (c >> 8) * WM_TAP + (c & 255) * 16,
                  (char*)Alds + (i * 256 + wv * 64) * 16);
        }
#pragma unroll
        for (int i = 0; i < 10; ++i) {         // B: 2320 real + 240 pad chunks
            int c = i * 256 + tid;
            GLL16(bg + c * 16,
                  (char*)Blds + (i * 256 + wv * 64) * 16);
        }
        __syncthreads();   // staging drained

#pragma unroll
        for (int tap = 0; tap < 9; ++tap) {
            const int kh = tap / 3, kw = tap - kh * 3;
            const int shift = (kh * XT_R + kw) * 64;
            short8 af[4];
#pragma unroll
            for (int mi = 0; mi < 4; ++mi)
                af[mi] = *(const short8*)((const char*)Alds + tap * 4096 + (mi * 16 + ln) * 64 + kg * 16);
            short8 bf[7];
#pragma unroll
            for (int ni = 0; ni < 7; ++ni)
                bf[ni] = *(const short8*)((const char*)Blds + pbase[ni] * 64 + shift + kg * 16);
#pragma unroll
            for (int mi = 0; mi < 4; ++mi)
#pragma unroll
                for (int ni = 0; ni < 7; ++ni)
                    acc[mi][ni] = __builtin_amdgcn_mfma_f32_16x16x32_bf16(
                        af[mi], bf[ni], acc[mi][ni], 0, 0, 0);
        }
    }

    // epilogue: C row(fo) = (lane>>4)*4 + r, col(px) = lane&15 (round-2-verified)
#pragma unroll
    for (int mi = 0; mi < 4; ++mi) {
#pragma unroll
        for (int r = 0; r < 4; ++r) {
            const int row = fo0 + mi * 16 + kg * 4 + r;
            const float bv = bias[row];
            float* op = out + ((size_t)(b * NCH + row)) * NPIX + rt * 448 + wv * 112;
#pragma unroll
            for (int ni = 0; ni < 7; ++ni)
                op[ni * 16 + ln] = acc[mi][ni][r] + bv;
        }
    }
}

// ---------------- round-1 fp32 fallback (ws too small) -----------------------------
#define XS_W 60
#define XS_H 58
#define NGROUPS (NPIX / 4)
__global__ __launch_bounds__(256) void conv_dwa_fp32(
    const float* __restrict__ x, const float* __restrict__ m,
    const float* __restrict__ weight, const float* __restrict__ bias,
    float* __restrict__ out) {
    __shared__ float xs[XS_H * XS_W];
    const int tid = threadIdx.x, blk = blockIdx.x;
    const int b = blk >> 8, fo = blk & 255;
    const float* xb = x + (size_t)b * NCH * NPIX;
    const float* mb = m + ((size_t)b * NCH + fo) * (NCH * 9);
    const float* wb = weight + (size_t)fo * (NCH * 9);
    float acc[4][4];
#pragma unroll
    for (int g = 0; g < 4; ++g)
#pragma unroll
        for (int i = 0; i < 4; ++i) acc[g][i] = 0.0f;
    int rowbase[4];
#pragma unroll
    for (int g = 0; g < 4; ++g) {
        int p0 = (tid + g * 256) * 4;
        int gh = p0 / HW;
        rowbase[g] = gh * XS_W + (p0 - gh * HW);
    }
    for (int fi = 0; fi < NCH; ++fi) {
        const float* xp = xb + (size_t)fi * NPIX;
        __syncthreads();
        for (int idx = tid; idx < XS_H * 58; idx += 256) {
            int hh = idx / 58, ww = idx - hh * 58;
            int h = hh - 1, w = ww - 1;
            float v = 0.0f;
            if ((unsigned)h < HW && (unsigned)w < HW) v = xp[h * HW + w];
            xs[hh * XS_W + ww] = v;
        }
        float wm9[9];
#pragma unroll
        for (int j = 0; j < 9; ++j) wm9[j] = wb[fi * 9 + j] * mb[fi * 9 + j];
        __syncthreads();
#pragma unroll
        for (int g = 0; g < 4; ++g) {
            if (tid + g * 256 >= NGROUPS) break;
            const float* row0 = &xs[rowbase[g]];
#pragma unroll
            for (int kh = 0; kh < 3; ++kh) {
                const float* r = row0 + kh * XS_W;
                float s0 = r[0], s1 = r[1], s2 = r[2], s3 = r[3], s4 = r[4], s5 = r[5];
                const float w0 = wm9[3 * kh], w1 = wm9[3 * kh + 1], w2 = wm9[3 * kh + 2];
                acc[g][0] = fmaf(s2, w2, fmaf(s1, w1, fmaf(s0, w0, acc[g][0])));
                acc[g][1] = fmaf(s3, w2, fmaf(s2, w1, fmaf(s1, w0, acc[g][1])));
                acc[g][2] = fmaf(s4, w2, fmaf(s3, w1, fmaf(s2, w0, acc[g][2])));
                acc[g][3] = fmaf(s5, w2, fmaf(s4, w1, fmaf(s3, w0, acc[g][3])));
            }
        }
    }
    const float bv = bias[fo];
    float* ob = out + ((size_t)b * NCH + fo) * NPIX;
#pragma unroll
    for (int g = 0; g < 4; ++g) {
        int gi = tid + g * 256;
        if (gi >= NGROUPS) break;
        float4 v;
        v.x = acc[g][0] + bv; v.y = acc[g][1] + bv;
        v.z = acc[g][2] + bv; v.w = acc[g][3] + bv;
        *(float4*)(ob + gi * 4) = v;
    }
}

extern "C" void kernel_launch(void* const* d_in, const int* in_sizes, int n_in,
                              void* d_out, int out_size, void* d_ws, size_t ws_size,
                              hipStream_t stream) {
    const float* x      = (const float*)d_in[0];
    const float* m      = (const float*)d_in[1];
    const float* weight = (const float*)d_in[2];
    const float* bias   = (const float*)d_in[3];
    float* out          = (float*)d_out;

    if (ws_size < WS_NEEDED) {   // constant across calls -> graph-safe
        conv_dwa_fp32<<<dim3(BATCH * NCH), dim3(256), 0, stream>>>(x, m, weight, bias, out);
        return;
    }

    char* xtb = (char*)d_ws;            // Xt first: gemm B-stage pad overruns into Wm (in-bounds)
    char* wmb = xtb + XT_BYTES;

    halo_zero<<<dim3(BATCH * 8), dim3(256), 0, stream>>>(xtb);
    wm_prep<<<dim3(BATCH * NCH), dim3(256), 0, stream>>>(weight, m, wmb);
    xt_prep<<<dim3(BATCH * HW), dim3(256), 0, stream>>>(x, xtb);
    gemm_dwa<<<dim3(896), dim3(256), 0, stream>>>(xtb, wmb, bias, out);
}